// Round 5
// baseline (40308.551 us; speedup 1.0000x reference)
//
#include <hip/hip_runtime.h>
#include <hip/hip_bf16.h>

// tanh-approx GELU (JAX default) and its exact derivative
__device__ __forceinline__ float gelu_f(float x) {
  const float c = 0.7978845608028654f;
  float u = c * (x + 0.044715f * x * x * x);
  float t = tanhf(u);
  return 0.5f * x * (1.f + t);
}
__device__ __forceinline__ float gelu_grad_f(float x) {
  const float c = 0.7978845608028654f;
  float x2 = x * x;
  float u = c * (x + 0.044715f * x2 * x);
  float t = tanhf(u);
  return 0.5f * (1.f + t) + 0.5f * x * (1.f - t * t) * c * (1.f + 0.134145f * x2);
}

// Agent-scope coherent (sc1) publish path for cross-block producer->consumer
// buffers. Consumers read PLAIN (L2-cached) after a per-phase acquire fence.
__device__ __forceinline__ void st_coh(float* p, float v) {
  __hip_atomic_store(p, v, __ATOMIC_RELAXED, __HIP_MEMORY_SCOPE_AGENT);
}

// ---------------------------------------------------------------------------
// Tiled fp32 GEMM (forward path). 64x64 tile, 16-deep K panel.
// ---------------------------------------------------------------------------
template<bool TRANSB, int ACT>
__global__ __launch_bounds__(256) void gemm_k(
    const float* __restrict__ A, const float* __restrict__ B, float* __restrict__ C,
    float* __restrict__ Zbuf, const float* __restrict__ bias,
    int M, int N, int K, int lda, int ldb,
    int P, int bsRows, int rowOff,
    const float* __restrict__ ci, int ciP, int ciBs, int ciOff,
    const float* __restrict__ delta, float gscale)
{
  __shared__ float As[16][68];
  __shared__ float Bs[16][68];
  const int bm = blockIdx.y * 64, bn = blockIdx.x * 64;
  const int tid = threadIdx.x;
  const int tr = tid >> 4, tc = tid & 15;
  float acc[4][4] = {};
  for (int k0 = 0; k0 < K; k0 += 16) {
    {
      const int e = tid * 4;
      const int m = e >> 4, kk = e & 15;
      const int gm = bm + m;
      const bool mv = gm < M;
      const long grow = (long)(gm / P) * bsRows + rowOff + (gm % P);
      const float* ap = A + grow * lda + k0 + kk;
      #pragma unroll
      for (int i = 0; i < 4; i++) {
        float v = 0.f;
        if (mv) v = ap[i];
        As[kk + i][m] = v;
      }
    }
    if (!TRANSB) {
      const int e = tid * 4;
      const int kk = e >> 6, n = e & 63;
      const int gn = bn + n;
      const float* bp = B + (long)(k0 + kk) * ldb + gn;
      #pragma unroll
      for (int i = 0; i < 4; i++) Bs[kk][n + i] = bp[i];
    } else {
      const int e = tid * 4;
      const int n = e >> 4, kk = e & 15;
      const int gn = bn + n;
      const float* bp = B + (long)gn * ldb + k0 + kk;
      #pragma unroll
      for (int i = 0; i < 4; i++) Bs[kk + i][n] = bp[i];
    }
    __syncthreads();
    #pragma unroll
    for (int kk = 0; kk < 16; kk++) {
      float a[4], b[4];
      #pragma unroll
      for (int i = 0; i < 4; i++) a[i] = As[kk][tr * 4 + i];
      #pragma unroll
      for (int j = 0; j < 4; j++) b[j] = Bs[kk][tc * 4 + j];
      #pragma unroll
      for (int i = 0; i < 4; i++)
        #pragma unroll
        for (int j = 0; j < 4; j++) acc[i][j] += a[i] * b[j];
    }
    __syncthreads();
  }
  #pragma unroll
  for (int i = 0; i < 4; i++) {
    const int m = bm + tr * 4 + i;
    if (m >= M) continue;
    #pragma unroll
    for (int j = 0; j < 4; j++) {
      const int n = bn + tc * 4 + j;
      if (n >= N) continue;
      float v = acc[i][j];
      if (bias) v += bias[n];
      if (ACT == 1) {
        if (Zbuf) Zbuf[(long)m * N + n] = v;
        v = gelu_f(v);
      } else if (ACT == 2) {
        const long crow = (long)(m / ciP) * ciBs + ciOff + (m % ciP);
        const float tgt = ci[crow * 1024 + n] + delta[(m / ciP) * 1024 + n];
        v = gscale * (v - tgt);
      } else if (ACT == 3) {
        v = v * gelu_grad_f(Zbuf[(long)m * N + n]);
      }
      C[(long)m * N + n] = v;
    }
  }
}

// ---------------------------------------------------------------------------
// Flash-style causal attention. q-tiles launched longest-first (tail balance).
// ---------------------------------------------------------------------------
__global__ __launch_bounds__(256) void attn_kernel(
    const float* __restrict__ Q, const float* __restrict__ K,
    const float* __restrict__ V, float* __restrict__ ctx)
{
  const int S = 2048, D = 1024;
  const int qt = (int)gridDim.x - 1 - (int)blockIdx.x;  // longest blocks first
  const int h = blockIdx.y, b = blockIdx.z;
  const int q0 = qt * 64;
  __shared__ float Qs[64][65];
  __shared__ float Ks[32][65];
  __shared__ float Vs[32][65];
  __shared__ float Ss[64][33];
  const int tid = threadIdx.x;
  for (int e = tid; e < 4096; e += 256) {
    int r = e >> 6, d = e & 63;
    Qs[r][d] = Q[(long)(b * S + q0 + r) * D + h * 64 + d];
  }
  const int r = tid >> 2;
  const int g = tid & 3;
  const int dg8 = g * 8;
  const int dg16 = g * 16;
  float acc[16];
  #pragma unroll
  for (int i = 0; i < 16; i++) acc[i] = 0.f;
  float mrow = -1e30f, lrow = 0.f;
  for (int k0 = 0; k0 < q0 + 64; k0 += 32) {
    __syncthreads();
    for (int e = tid; e < 2048; e += 256) {
      int rr = e >> 6, d = e & 63;
      Ks[rr][d] = K[(long)(b * S + k0 + rr) * D + h * 64 + d];
      Vs[rr][d] = V[(long)(b * S + k0 + rr) * D + h * 64 + d];
    }
    __syncthreads();
    float sc[8];
    #pragma unroll
    for (int j = 0; j < 8; j++) sc[j] = 0.f;
    for (int d = 0; d < 64; d++) {
      float qd = Qs[r][d];
      #pragma unroll
      for (int j = 0; j < 8; j++) sc[j] += qd * Ks[dg8 + j][d];
    }
    float tmax = -1e30f;
    #pragma unroll
    for (int j = 0; j < 8; j++) {
      sc[j] *= 0.125f;
      if (k0 + dg8 + j > q0 + r) sc[j] = -1e30f;
      tmax = fmaxf(tmax, sc[j]);
    }
    tmax = fmaxf(tmax, __shfl_xor(tmax, 1));
    tmax = fmaxf(tmax, __shfl_xor(tmax, 2));
    const float newm = fmaxf(mrow, tmax);
    const float scale = __expf(mrow - newm);
    float psum = 0.f;
    #pragma unroll
    for (int j = 0; j < 8; j++) {
      sc[j] = __expf(sc[j] - newm);
      psum += sc[j];
    }
    psum += __shfl_xor(psum, 1);
    psum += __shfl_xor(psum, 2);
    lrow = lrow * scale + psum;
    mrow = newm;
    #pragma unroll
    for (int i = 0; i < 16; i++) acc[i] *= scale;
    #pragma unroll
    for (int j = 0; j < 8; j++) Ss[r][dg8 + j] = sc[j];
    __syncthreads();
    for (int c = 0; c < 32; c++) {
      float p = Ss[r][c];
      #pragma unroll
      for (int i = 0; i < 16; i++) acc[i] += p * Vs[c][dg16 + i];
    }
  }
  const float inv = 1.f / lrow;
  #pragma unroll
  for (int i = 0; i < 16; i++)
    ctx[(long)(b * S + q0 + r) * D + h * 64 + dg16 + i] = acc[i] * inv;
}

// Per-chunk teach means for both levels (unchanged).
__global__ void compute_deltas(const float* __restrict__ teach,
                               float* __restrict__ dF, float* __restrict__ dS)
{
  const int nF = 128 * 2048;
  const int nS = 32 * 2048;
  int t = blockIdx.x * blockDim.x + threadIdx.x;
  if (t < nF) {
    int c = t >> 11, b = (t >> 10) & 1, d = t & 1023;
    long base = ((long)(b * 2048 + c * 16)) * 1024 + d;
    float s = 0.f;
    for (int k = 0; k < 16; k++) s += teach[base + (long)k * 1024];
    dF[t] = s * (1.f / 16.f);
  } else if (t < nF + nS) {
    int u = t - nF;
    int c = u >> 11, b = (u >> 10) & 1, d = u & 1023;
    long base = ((long)(b * 2048 + c * 64)) * 1024 + d;
    float s = 0.f;
    for (int k = 0; k < 64; k++) s += teach[base + (long)k * 1024];
    dS[u] = s * (1.f / 64.f);
  }
}

// ---------------------------------------------------------------------------
// Grid barrier: relaxed agent atomics only (proven round 4).
// ---------------------------------------------------------------------------
__device__ __forceinline__ void grid_bar(int* cnt, int target) {
  __syncthreads();
  if (threadIdx.x == 0) {
    __hip_atomic_fetch_add(cnt, 1, __ATOMIC_RELAXED, __HIP_MEMORY_SCOPE_AGENT);
    int spins = 0;
    while (__hip_atomic_load(cnt, __ATOMIC_RELAXED, __HIP_MEMORY_SCOPE_AGENT) < target) {
      __builtin_amdgcn_s_sleep(2);
      if (++spins > (1 << 20)) break;   // bailout: corrupt, don't hang
    }
  }
  __syncthreads();
}

// ---------------------------------------------------------------------------
// Fused TTT scan, fully on-chip weights. 256 blocks x 512 threads.
// Block b owns for the WHOLE scan:
//   LDS:  W1 cols [16b,16b+16)  (w1s)      | W2 rows [16b,16b+16) (w2rs)
//         b1[16b..+16) (b1s)               | b2[4b..4b+4) (b2s)
//   REGS: W2 cols [4b,4b+4)     (w2c: k = i*2048 + 4*tid + e, 32 VGPR)
// Global weights touched ONLY at init load + final writeback.
// Cross-block: abuf/Gbuf published sc1, read PLAIN after per-phase
// acquire("agent") fence (L2 invalidate) -> XCD-L2 dedupes the broadcast.
// Phases: p1 (z,a->abuf) | BAR+INV | p2 (butterfly pred -> G, b2s, w2c upd)
//         | BAR+INV | p3 (dZ + w2rs row update + b1s) | p4a (w1s update).
// ---------------------------------------------------------------------------
#define ACCR(pp, a, ii) \
  pp.x += a.x*w2c[ii][0].x + a.y*w2c[ii][1].x + a.z*w2c[ii][2].x + a.w*w2c[ii][3].x; \
  pp.y += a.x*w2c[ii][0].y + a.y*w2c[ii][1].y + a.z*w2c[ii][2].y + a.w*w2c[ii][3].y; \
  pp.z += a.x*w2c[ii][0].z + a.y*w2c[ii][1].z + a.z*w2c[ii][2].z + a.w*w2c[ii][3].z; \
  pp.w += a.x*w2c[ii][0].w + a.y*w2c[ii][1].w + a.z*w2c[ii][2].w + a.w*w2c[ii][3].w;

#define P2ACC(ii) { \
  const float* ab = abuf + (long)(g * 4) * 4096 + (ii) * 2048 + 4 * tid; \
  float4 a0 = *(const float4*)&ab[0]; \
  float4 a1 = *(const float4*)&ab[4096]; \
  float4 a2 = *(const float4*)&ab[8192]; \
  float4 a3 = *(const float4*)&ab[12288]; \
  ACCR(pp0, a0, ii) ACCR(pp1, a1, ii) ACCR(pp2, a2, ii) ACCR(pp3, a3, ii) }

#define BFLY(v) { v.x += __shfl_xor(v.x, off); v.y += __shfl_xor(v.y, off); \
                  v.z += __shfl_xor(v.z, off); v.w += __shfl_xor(v.w, off); }

#define W2CUPD(ii) { \
  float4 u0 = make_float4(0,0,0,0), u1 = u0, u2 = u0, u3 = u0; \
  const float* ab = abuf + (ii) * 2048 + 4 * tid; \
  _Pragma("unroll 4") \
  for (int r = 0; r < R; r++) { \
    float4 a4 = *(const float4*)&ab[(long)r * 4096]; \
    float4 g4 = *(const float4*)&gc[r * 4]; \
    u0.x += a4.x*g4.x; u0.y += a4.x*g4.y; u0.z += a4.x*g4.z; u0.w += a4.x*g4.w; \
    u1.x += a4.y*g4.x; u1.y += a4.y*g4.y; u1.z += a4.y*g4.z; u1.w += a4.y*g4.w; \
    u2.x += a4.z*g4.x; u2.y += a4.z*g4.y; u2.z += a4.z*g4.z; u2.w += a4.z*g4.w; \
    u3.x += a4.w*g4.x; u3.y += a4.w*g4.y; u3.z += a4.w*g4.z; u3.w += a4.w*g4.w; } \
  w2c[ii][0].x -= LR*u0.x; w2c[ii][0].y -= LR*u0.y; w2c[ii][0].z -= LR*u0.z; w2c[ii][0].w -= LR*u0.w; \
  w2c[ii][1].x -= LR*u1.x; w2c[ii][1].y -= LR*u1.y; w2c[ii][1].z -= LR*u1.z; w2c[ii][1].w -= LR*u1.w; \
  w2c[ii][2].x -= LR*u2.x; w2c[ii][2].y -= LR*u2.y; w2c[ii][2].z -= LR*u2.z; w2c[ii][2].w -= LR*u2.w; \
  w2c[ii][3].x -= LR*u3.x; w2c[ii][3].y -= LR*u3.y; w2c[ii][3].z -= LR*u3.z; w2c[ii][3].w -= LR*u3.w; }

template<int P, int NC>
__global__ __launch_bounds__(512, 1) void ttt_fused(
    const float* __restrict__ lin, const float* __restrict__ dlt,
    float* __restrict__ W1, float* __restrict__ b1,
    float* __restrict__ W2, float* __restrict__ b2,
    float* __restrict__ abuf, float* __restrict__ Gbuf, int* __restrict__ bar)
{
  constexpr int R = 2 * P;             // rows per chunk (both batches)
  constexpr int RPT = R / 32;          // rows per thread in p1/p3
  constexpr float GS = 2.f / (float)R;
  constexpr float LR = 1e-3f;
  constexpr int ST = R + 4;
  // LDS layout (floats)
  constexpr int O_W2R = 16384;
  constexpr int O_SCR = O_W2R + 16 * 1028;
  constexpr int SCRSZ = R * 36;                 // >= 8*R*4 partial area
  constexpr int O_ATD = O_SCR + SCRSZ;
  constexpr int O_GC  = O_ATD + 16 * ST;
  constexpr int O_B   = O_GC + R * 4;
  constexpr int SMTOT = O_B + 24;   // slow: 40,088 fl = 160,352 B (<160KiB)

  __shared__ float smem[SMTOT];
  float* w1s  = smem;                // [1024][16] W1 own cols
  float* w2rs = smem + O_W2R;        // [16][1028] W2 own rows
  float* scr  = smem + O_SCR;        // [R][36] staging / [8][R*4] partials
  float* atd  = smem + O_ATD;        // [16][ST] a^T then dZ^T (own cols)
  float* gc   = smem + O_GC;         // [R][4] G own cols
  float* b1s  = smem + O_B;          // [16]
  float* b2s  = smem + O_B + 16;     // [4]

  const int bid = blockIdx.x, tid = threadIdx.x;
  const int j0 = bid * 16, c0 = bid * 4;
  const int rg = tid >> 4, jj = tid & 15;
  const int jB = tid >> 5, dB = tid & 31;      // p3-B roles
  const int kkA = tid >> 4, jjA = tid & 15;    // p4a roles
  const int NB = gridDim.x;
  int ep = 0;

  // ---- init: resident weight slices (only global weight reads) ----
  for (int q = tid; q < 16384; q += 512) {
    int k = q >> 4, j = q & 15;
    w1s[k * 16 + j] = W1[(long)k * 4096 + j0 + j];
  }
  for (int q = tid; q < 16384; q += 512) {
    int j = q >> 10, d = q & 1023;
    w2rs[j * 1028 + d] = W2[(long)(j0 + j) * 1024 + d];
  }
  float4 w2c[2][4];
  #pragma unroll
  for (int i = 0; i < 2; i++)
    #pragma unroll
    for (int e = 0; e < 4; e++)
      w2c[i][e] = *(const float4*)&W2[(long)(i * 2048 + 4 * tid + e) * 1024 + c0];
  if (tid < 16) b1s[tid] = b1[j0 + tid];
  if (tid < 4)  b2s[tid] = b2[c0 + tid];
  __syncthreads();

  for (int c = 0; c < NC; c++) {
    const int rb0 = c * P, rb1 = 2048 - P + c * P;
    float zf[RPT];
    // ---------------- p1: z = ci@W1 + b1 ; a = gelu(z) -> atd, abuf ------
    {
      float zacc[RPT];
      #pragma unroll
      for (int i = 0; i < RPT; i++) zacc[i] = 0.f;
      for (int kp = 0; kp < 1024; kp += 32) {
        for (int q = tid; q < R * 8; q += 512) {
          const int r = q >> 3, k4 = (q & 7) * 4;
          const long grow = (r < P) ? (long)(rb0 + r) : (long)(rb1 + r);
          *(float4*)&scr[r * 36 + k4] = *(const float4*)&lin[grow * 1024 + kp + k4];
        }
        __syncthreads();
        #pragma unroll
        for (int k4 = 0; k4 < 8; k4++) {
          const float w0  = w1s[(kp + k4 * 4 + 0) * 16 + jj];
          const float w1v = w1s[(kp + k4 * 4 + 1) * 16 + jj];
          const float w2v = w1s[(kp + k4 * 4 + 2) * 16 + jj];
          const float w3v = w1s[(kp + k4 * 4 + 3) * 16 + jj];
          #pragma unroll
          for (int i = 0; i < RPT; i++) {
            const float4 c4 = *(const float4*)&scr[(rg * RPT + i) * 36 + k4 * 4];
            zacc[i] += c4.x * w0 + c4.y * w1v + c4.z * w2v + c4.w * w3v;
          }
        }
        __syncthreads();
      }
      const float b1v = b1s[jj];
      #pragma unroll
      for (int i = 0; i < RPT; i++) {
        const int r = rg * RPT + i;
        zf[i] = zacc[i] + b1v;
        const float a = gelu_f(zf[i]);
        atd[jj * ST + r] = a;
        st_coh(&abuf[(long)r * 4096 + j0 + jj], a);
      }
    }
    ++ep; grid_bar(bar, ep * NB);
    __builtin_amdgcn_fence(__ATOMIC_ACQUIRE, "agent");  // inv: fresh abuf
    // ------- p2: pred = a@W2 + b2 for own 4 cols (W2 cols in regs) -------
    {
      for (int g = 0; g < R / 4; g++) {
        float4 pp0 = make_float4(0,0,0,0), pp1 = pp0, pp2 = pp0, pp3 = pp0;
        P2ACC(0)
        P2ACC(1)
        #pragma unroll
        for (int off = 1; off < 64; off <<= 1) { BFLY(pp0) BFLY(pp1) BFLY(pp2) BFLY(pp3) }
        if ((tid & 63) == 0) {
          const int wv = tid >> 6;
          float* dst = &scr[wv * (R * 4) + g * 16];
          *(float4*)&dst[0]  = pp0;  *(float4*)&dst[4]  = pp1;
          *(float4*)&dst[8]  = pp2;  *(float4*)&dst[12] = pp3;
        }
      }
      __syncthreads();
      if (tid < R * 4) {
        const int r = tid >> 2, cc = tid & 3;
        float s = 0.f;
        #pragma unroll
        for (int wv = 0; wv < 8; wv++) s += scr[wv * (R * 4) + tid];
        const long grow = (r < P) ? (long)(rb0 + r) : (long)(rb1 + r);
        const int col = c0 + cc;
        const float tgt = lin[grow * 1024 + col]
                        + dlt[(long)(2 * c + (r >= P ? 1 : 0)) * 1024 + col];
        const float Gv = GS * (s + b2s[cc] - tgt);
        st_coh(&Gbuf[(long)r * 1024 + col], Gv);
        gc[tid] = Gv;
      }
      __syncthreads();
      if (tid < 4) {
        float s = 0.f;
        for (int r = 0; r < R; r++) s += gc[r * 4 + tid];
        b2s[tid] -= LR * s;
      }
      // register W2-col update from L2-hot abuf + gc
      W2CUPD(0)
      W2CUPD(1)
    }
    ++ep; grid_bar(bar, ep * NB);
    __builtin_amdgcn_fence(__ATOMIC_ACQUIRE, "agent");  // inv: fresh Gbuf
    // ---------------- p3: dZ = (G@W2^T)*gelu'(z); w2rs row update --------
    {
      float dzacc[RPT];
      #pragma unroll
      for (int i = 0; i < RPT; i++) dzacc[i] = 0.f;
      for (int dp = 0; dp < 1024; dp += 32) {
        for (int q = tid; q < R * 8; q += 512) {
          const int r = q >> 3, d4 = (q & 7) * 4;
          *(float4*)&scr[r * 36 + d4] = *(const float4*)&Gbuf[(long)r * 1024 + dp + d4];
        }
        __syncthreads();
        // A: dZ partial (PRE-update W2 rows from LDS)
        #pragma unroll
        for (int d4 = 0; d4 < 8; d4++) {
          const float4 w4 = *(const float4*)&w2rs[jj * 1028 + dp + d4 * 4];
          #pragma unroll
          for (int i = 0; i < RPT; i++) {
            const float4 g4 = *(const float4*)&scr[(rg * RPT + i) * 36 + d4 * 4];
            dzacc[i] += g4.x * w4.x + g4.y * w4.y + g4.z * w4.z + g4.w * w4.w;
          }
        }
        __syncthreads();   // A must finish before B writes w2rs
        // B: W2 row-panel rank-R update (LDS only; global write at end)
        {
          float s = 0.f;
          #pragma unroll 4
          for (int r = 0; r < R; r++) s += atd[jB * ST + r] * scr[r * 36 + dB];
          w2rs[jB * 1028 + dp + dB] -= LR * s;
        }
        __syncthreads();
      }
      float bsum = 0.f;
      #pragma unroll
      for (int i = 0; i < RPT; i++) {
        const int r = rg * RPT + i;
        const float dz = dzacc[i] * gelu_grad_f(zf[i]);
        atd[jj * ST + r] = dz;
        bsum += dz;
      }
      scr[tid] = bsum;
      __syncthreads();
      if (tid < 16) {
        float s = 0.f;
        #pragma unroll
        for (int g2 = 0; g2 < 32; g2++) s += scr[g2 * 16 + tid];
        b1s[tid] -= LR * s;
      }
      __syncthreads();
    }
    // ---------------- p4a: W1 own-col update (LDS-resident) --------------
    {
      for (int kp = 0; kp < 1024; kp += 32) {
        for (int q = tid; q < R * 8; q += 512) {
          const int r = q >> 3, k4 = (q & 7) * 4;
          const long grow = (r < P) ? (long)(rb0 + r) : (long)(rb1 + r);
          *(float4*)&scr[r * 36 + k4] = *(const float4*)&lin[grow * 1024 + kp + k4];
        }
        __syncthreads();
        float s = 0.f;
        #pragma unroll 4
        for (int r4 = 0; r4 < R; r4 += 4) {
          const float4 d4 = *(const float4*)&atd[jjA * ST + r4];
          s += scr[(r4 + 0) * 36 + kkA] * d4.x + scr[(r4 + 1) * 36 + kkA] * d4.y
             + scr[(r4 + 2) * 36 + kkA] * d4.z + scr[(r4 + 3) * 36 + kkA] * d4.w;
        }
        w1s[(kp + kkA) * 16 + jjA] -= LR * s;
        __syncthreads();
      }
    }
    // no grid barrier at chunk end: abuf rewrite races are fenced by BAR1
    // (all blocks finished p2 before any block passes next BAR1)
  }

  // ---- final writeback of all resident state ----
  for (int q = tid; q < 16384; q += 512) {
    int k = q >> 4, j = q & 15;
    W1[(long)k * 4096 + j0 + j] = w1s[k * 16 + j];
  }
  for (int q = tid; q < 16384; q += 512) {
    int j = q >> 10, d = q & 1023;
    W2[(long)(j0 + j) * 1024 + d] = w2rs[j * 1028 + d];
  }
  if (tid < 16) b1[j0 + tid] = b1s[tid];
  if (tid < 4)  b2[c0 + tid] = b2s[tid];
}

extern "C" void kernel_launch(void* const* d_in, const int* in_sizes, int n_in,
                              void* d_out, int out_size, void* d_ws, size_t ws_size,
                              hipStream_t stream) {
  const float* x     = (const float*)d_in[0];
  const float* teach = (const float*)d_in[1];
  const float* wq    = (const float*)d_in[2];
  const float* wk    = (const float*)d_in[3];
  const float* wv    = (const float*)d_in[4];
  const float* wo    = (const float*)d_in[5];
  float* out = (float*)d_out;
  float* ws  = (float*)d_ws;

  // ---- d_out layout (floats): cms_out, then the 8 updated params ----
  const long P_W1F = 4194304;
  const long P_B1F = 8388608;
  const long P_W2F = 8392704;
  const long P_B2F = 12587008;
  const long P_W1S = 12588032;
  const long P_B1S = 16782336;
  const long P_W2S = 16786432;
  const long P_B2S = 20980736;

  // ---- ws layout (floats) ----
  const long O_Q   = 0;
  const long O_K   = 4194304;
  const long O_V   = 8388608;
  const long O_CTX = 12582912;
  const long O_H   = 0;          // MLP hidden [4096,4096] (fwd; overlays QKV/CTX)
  const long O_AB  = 0;          // TTT abuf [R,4096]
  const long O_GB  = 524288;     // TTT Gbuf [R,1024]
  const long O_BAR = 12582912;   // TTT grid-barrier counter (dead CTX region)
  const long O_INF = 16787456;   // in_fast [4096,1024]
  const long O_INS = 20981760;   // in_slow [4096,1024]
  const long O_DF  = 25176064;   // 262,144
  const long O_DS  = 25438208;   // 65,536

  // --- seed fp32 masters directly into d_out (updated in place by TTT) ---
  {
    const long poff[8] = {P_W1F, P_B1F, P_W2F, P_B2F, P_W1S, P_B1S, P_W2S, P_B2S};
    const size_t psz[8] = {4194304, 4096, 4194304, 1024, 4194304, 4096, 4194304, 1024};
    for (int i = 0; i < 8; i++)
      hipMemcpyAsync(out + poff[i], d_in[6 + i], psz[i] * sizeof(float),
                     hipMemcpyDeviceToDevice, stream);
  }

  // --- per-chunk teach means ---
  compute_deltas<<<dim3(1281), 256, 0, stream>>>(teach, ws + O_DF, ws + O_DS);

  // --- Q/K/V projections ---
  {
    dim3 grd(16, 64);
    gemm_k<false, 0><<<grd, 256, 0, stream>>>(
        x, wq, ws + O_Q, nullptr, nullptr, 4096, 1024, 1024, 1024, 1024,
        4096, 0, 0, nullptr, 1, 0, 0, nullptr, 0.f);
    gemm_k<false, 0><<<grd, 256, 0, stream>>>(
        x, wk, ws + O_K, nullptr, nullptr, 4096, 1024, 1024, 1024, 1024,
        4096, 0, 0, nullptr, 1, 0, 0, nullptr, 0.f);
    gemm_k<false, 0><<<grd, 256, 0, stream>>>(
        x, wv, ws + O_V, nullptr, nullptr, 4096, 1024, 1024, 1024, 1024,
        4096, 0, 0, nullptr, 1, 0, 0, nullptr, 0.f);
  }

  // --- causal attention ---
  attn_kernel<<<dim3(32, 16, 2), 256, 0, stream>>>(ws + O_Q, ws + O_K, ws + O_V, ws + O_CTX);

  // --- in_fast = ctx @ wo ---
  gemm_k<false, 0><<<dim3(16, 64), 256, 0, stream>>>(
      ws + O_CTX, wo, ws + O_INF, nullptr, nullptr, 4096, 1024, 1024, 1024, 1024,
      4096, 0, 0, nullptr, 1, 0, 0, nullptr, 0.f);

  // --- MLP forwards with BASE params; full-width hidden buffer ---
  gemm_k<false, 1><<<dim3(64, 64), 256, 0, stream>>>(
      ws + O_INF, out + P_W1F, ws + O_H, nullptr, out + P_B1F,
      4096, 4096, 1024, 1024, 4096, 4096, 0, 0, nullptr, 1, 0, 0, nullptr, 0.f);
  gemm_k<false, 0><<<dim3(16, 64), 256, 0, stream>>>(
      ws + O_H, out + P_W2F, ws + O_INS, nullptr, out + P_B2F,
      4096, 1024, 4096, 4096, 1024, 4096, 0, 0, nullptr, 1, 0, 0, nullptr, 0.f);
  gemm_k<false, 1><<<dim3(64, 64), 256, 0, stream>>>(
      ws + O_INS, out + P_W1S, ws + O_H, nullptr, out + P_B1S,
      4096, 4096, 1024, 1024, 4096, 4096, 0, 0, nullptr, 1, 0, 0, nullptr, 0.f);
  gemm_k<false, 0><<<dim3(16, 64), 256, 0, stream>>>(
      ws + O_H, out + P_W2S, out, nullptr, out + P_B2S,
      4096, 1024, 4096, 4096, 1024, 4096, 0, 0, nullptr, 1, 0, 0, nullptr, 0.f);

  // --- TTT updates: ONE persistent kernel per level, weights on-chip ---
  hipMemsetAsync(ws + O_BAR, 0, 256, stream);
  ttt_fused<16, 128><<<dim3(256), dim3(512), 0, stream>>>(
      ws + O_INF, ws + O_DF, out + P_W1F, out + P_B1F, out + P_W2F, out + P_B2F,
      ws + O_AB, ws + O_GB, (int*)(ws + O_BAR));
  hipMemsetAsync(ws + O_BAR, 0, 256, stream);
  ttt_fused<64, 32><<<dim3(256), dim3(512), 0, stream>>>(
      ws + O_INS, ws + O_DS, out + P_W1S, out + P_B1S, out + P_W2S, out + P_B2S,
      ws + O_AB, ws + O_GB, (int*)(ws + O_BAR));
}

// Round 6
// 34836.392 us; speedup vs baseline: 1.1571x; 1.1571x over previous
//
#include <hip/hip_runtime.h>
#include <hip/hip_bf16.h>

// tanh-approx GELU (JAX default) and its exact derivative
__device__ __forceinline__ float gelu_f(float x) {
  const float c = 0.7978845608028654f;
  float u = c * (x + 0.044715f * x * x * x);
  float t = tanhf(u);
  return 0.5f * x * (1.f + t);
}
__device__ __forceinline__ float gelu_grad_f(float x) {
  const float c = 0.7978845608028654f;
  float x2 = x * x;
  float u = c * (x + 0.044715f * x2 * x);
  float t = tanhf(u);
  return 0.5f * (1.f + t) + 0.5f * x * (1.f - t * t) * c * (1.f + 0.134145f * x2);
}

// Agent-scope coherent (sc1) publish path for cross-block producer->consumer
// buffers. Consumers read PLAIN (L2-cached) after a per-phase acquire fence.
__device__ __forceinline__ void st_coh(float* p, float v) {
  __hip_atomic_store(p, v, __ATOMIC_RELAXED, __HIP_MEMORY_SCOPE_AGENT);
}

// ---------------------------------------------------------------------------
// Tiled fp32 GEMM (forward path). 64x64 tile, 16-deep K panel.
// ---------------------------------------------------------------------------
template<bool TRANSB, int ACT>
__global__ __launch_bounds__(256) void gemm_k(
    const float* __restrict__ A, const float* __restrict__ B, float* __restrict__ C,
    float* __restrict__ Zbuf, const float* __restrict__ bias,
    int M, int N, int K, int lda, int ldb,
    int P, int bsRows, int rowOff,
    const float* __restrict__ ci, int ciP, int ciBs, int ciOff,
    const float* __restrict__ delta, float gscale)
{
  __shared__ float As[16][68];
  __shared__ float Bs[16][68];
  const int bm = blockIdx.y * 64, bn = blockIdx.x * 64;
  const int tid = threadIdx.x;
  const int tr = tid >> 4, tc = tid & 15;
  float acc[4][4] = {};
  for (int k0 = 0; k0 < K; k0 += 16) {
    {
      const int e = tid * 4;
      const int m = e >> 4, kk = e & 15;
      const int gm = bm + m;
      const bool mv = gm < M;
      const long grow = (long)(gm / P) * bsRows + rowOff + (gm % P);
      const float* ap = A + grow * lda + k0 + kk;
      #pragma unroll
      for (int i = 0; i < 4; i++) {
        float v = 0.f;
        if (mv) v = ap[i];
        As[kk + i][m] = v;
      }
    }
    if (!TRANSB) {
      const int e = tid * 4;
      const int kk = e >> 6, n = e & 63;
      const int gn = bn + n;
      const float* bp = B + (long)(k0 + kk) * ldb + gn;
      #pragma unroll
      for (int i = 0; i < 4; i++) Bs[kk][n + i] = bp[i];
    } else {
      const int e = tid * 4;
      const int n = e >> 4, kk = e & 15;
      const int gn = bn + n;
      const float* bp = B + (long)gn * ldb + k0 + kk;
      #pragma unroll
      for (int i = 0; i < 4; i++) Bs[kk + i][n] = bp[i];
    }
    __syncthreads();
    #pragma unroll
    for (int kk = 0; kk < 16; kk++) {
      float a[4], b[4];
      #pragma unroll
      for (int i = 0; i < 4; i++) a[i] = As[kk][tr * 4 + i];
      #pragma unroll
      for (int j = 0; j < 4; j++) b[j] = Bs[kk][tc * 4 + j];
      #pragma unroll
      for (int i = 0; i < 4; i++)
        #pragma unroll
        for (int j = 0; j < 4; j++) acc[i][j] += a[i] * b[j];
    }
    __syncthreads();
  }
  #pragma unroll
  for (int i = 0; i < 4; i++) {
    const int m = bm + tr * 4 + i;
    if (m >= M) continue;
    #pragma unroll
    for (int j = 0; j < 4; j++) {
      const int n = bn + tc * 4 + j;
      if (n >= N) continue;
      float v = acc[i][j];
      if (bias) v += bias[n];
      if (ACT == 1) {
        if (Zbuf) Zbuf[(long)m * N + n] = v;
        v = gelu_f(v);
      } else if (ACT == 2) {
        const long crow = (long)(m / ciP) * ciBs + ciOff + (m % ciP);
        const float tgt = ci[crow * 1024 + n] + delta[(m / ciP) * 1024 + n];
        v = gscale * (v - tgt);
      } else if (ACT == 3) {
        v = v * gelu_grad_f(Zbuf[(long)m * N + n]);
      }
      C[(long)m * N + n] = v;
    }
  }
}

// ---------------------------------------------------------------------------
// Flash-style causal attention. q-tiles launched longest-first (tail balance).
// ---------------------------------------------------------------------------
__global__ __launch_bounds__(256) void attn_kernel(
    const float* __restrict__ Q, const float* __restrict__ K,
    const float* __restrict__ V, float* __restrict__ ctx)
{
  const int S = 2048, D = 1024;
  const int qt = (int)gridDim.x - 1 - (int)blockIdx.x;  // longest blocks first
  const int h = blockIdx.y, b = blockIdx.z;
  const int q0 = qt * 64;
  __shared__ float Qs[64][65];
  __shared__ float Ks[32][65];
  __shared__ float Vs[32][65];
  __shared__ float Ss[64][33];
  const int tid = threadIdx.x;
  for (int e = tid; e < 4096; e += 256) {
    int r = e >> 6, d = e & 63;
    Qs[r][d] = Q[(long)(b * S + q0 + r) * D + h * 64 + d];
  }
  const int r = tid >> 2;
  const int g = tid & 3;
  const int dg8 = g * 8;
  const int dg16 = g * 16;
  float acc[16];
  #pragma unroll
  for (int i = 0; i < 16; i++) acc[i] = 0.f;
  float mrow = -1e30f, lrow = 0.f;
  for (int k0 = 0; k0 < q0 + 64; k0 += 32) {
    __syncthreads();
    for (int e = tid; e < 2048; e += 256) {
      int rr = e >> 6, d = e & 63;
      Ks[rr][d] = K[(long)(b * S + k0 + rr) * D + h * 64 + d];
      Vs[rr][d] = V[(long)(b * S + k0 + rr) * D + h * 64 + d];
    }
    __syncthreads();
    float sc[8];
    #pragma unroll
    for (int j = 0; j < 8; j++) sc[j] = 0.f;
    for (int d = 0; d < 64; d++) {
      float qd = Qs[r][d];
      #pragma unroll
      for (int j = 0; j < 8; j++) sc[j] += qd * Ks[dg8 + j][d];
    }
    float tmax = -1e30f;
    #pragma unroll
    for (int j = 0; j < 8; j++) {
      sc[j] *= 0.125f;
      if (k0 + dg8 + j > q0 + r) sc[j] = -1e30f;
      tmax = fmaxf(tmax, sc[j]);
    }
    tmax = fmaxf(tmax, __shfl_xor(tmax, 1));
    tmax = fmaxf(tmax, __shfl_xor(tmax, 2));
    const float newm = fmaxf(mrow, tmax);
    const float scale = __expf(mrow - newm);
    float psum = 0.f;
    #pragma unroll
    for (int j = 0; j < 8; j++) {
      sc[j] = __expf(sc[j] - newm);
      psum += sc[j];
    }
    psum += __shfl_xor(psum, 1);
    psum += __shfl_xor(psum, 2);
    lrow = lrow * scale + psum;
    mrow = newm;
    #pragma unroll
    for (int i = 0; i < 16; i++) acc[i] *= scale;
    #pragma unroll
    for (int j = 0; j < 8; j++) Ss[r][dg8 + j] = sc[j];
    __syncthreads();
    for (int c = 0; c < 32; c++) {
      float p = Ss[r][c];
      #pragma unroll
      for (int i = 0; i < 16; i++) acc[i] += p * Vs[c][dg16 + i];
    }
  }
  const float inv = 1.f / lrow;
  #pragma unroll
  for (int i = 0; i < 16; i++)
    ctx[(long)(b * S + q0 + r) * D + h * 64 + dg16 + i] = acc[i] * inv;
}

// Per-chunk teach means for both levels (unchanged).
__global__ void compute_deltas(const float* __restrict__ teach,
                               float* __restrict__ dF, float* __restrict__ dS)
{
  const int nF = 128 * 2048;
  const int nS = 32 * 2048;
  int t = blockIdx.x * blockDim.x + threadIdx.x;
  if (t < nF) {
    int c = t >> 11, b = (t >> 10) & 1, d = t & 1023;
    long base = ((long)(b * 2048 + c * 16)) * 1024 + d;
    float s = 0.f;
    for (int k = 0; k < 16; k++) s += teach[base + (long)k * 1024];
    dF[t] = s * (1.f / 16.f);
  } else if (t < nF + nS) {
    int u = t - nF;
    int c = u >> 11, b = (u >> 10) & 1, d = u & 1023;
    long base = ((long)(b * 2048 + c * 64)) * 1024 + d;
    float s = 0.f;
    for (int k = 0; k < 64; k++) s += teach[base + (long)k * 1024];
    dS[u] = s * (1.f / 64.f);
  }
}

// ---------------------------------------------------------------------------
// Grid barrier: relaxed agent atomics, 8 padded counters (cuts same-line
// RMW serialization of 256 arrivals ~8x). Monotonic; target = ep * nblocks.
// ---------------------------------------------------------------------------
__device__ __forceinline__ void grid_bar(int* cnt, int target) {
  __syncthreads();
  if (threadIdx.x == 0) {
    __hip_atomic_fetch_add(&cnt[(blockIdx.x & 7) * 32], 1,
                           __ATOMIC_RELAXED, __HIP_MEMORY_SCOPE_AGENT);
    int spins = 0;
    for (;;) {
      int s = 0;
      #pragma unroll
      for (int i = 0; i < 8; i++)
        s += __hip_atomic_load(&cnt[i * 32], __ATOMIC_RELAXED, __HIP_MEMORY_SCOPE_AGENT);
      if (s >= target) break;
      __builtin_amdgcn_s_sleep(2);
      if (++spins > (1 << 20)) break;   // bailout: corrupt, don't hang
    }
  }
  __syncthreads();
}

// ---------------------------------------------------------------------------
// Fused TTT scan, fully on-chip weights (round-5 ownership, proven correct).
// Round-6 changes: PAN-wide staged panels (fast 128, slow 32) + issue-early
// register prefetch in p1/p3/p4a -> syncs/chunk 230->~64, latency overlapped.
// ---------------------------------------------------------------------------
#define ACCR(pp, a, ii) \
  pp.x += a.x*w2c[ii][0].x + a.y*w2c[ii][1].x + a.z*w2c[ii][2].x + a.w*w2c[ii][3].x; \
  pp.y += a.x*w2c[ii][0].y + a.y*w2c[ii][1].y + a.z*w2c[ii][2].y + a.w*w2c[ii][3].y; \
  pp.z += a.x*w2c[ii][0].z + a.y*w2c[ii][1].z + a.z*w2c[ii][2].z + a.w*w2c[ii][3].z; \
  pp.w += a.x*w2c[ii][0].w + a.y*w2c[ii][1].w + a.z*w2c[ii][2].w + a.w*w2c[ii][3].w;

#define P2ACC(ii) { \
  const float* ab = abuf + (long)(g * 4) * 4096 + (ii) * 2048 + 4 * tid; \
  float4 a0 = *(const float4*)&ab[0]; \
  float4 a1 = *(const float4*)&ab[4096]; \
  float4 a2 = *(const float4*)&ab[8192]; \
  float4 a3 = *(const float4*)&ab[12288]; \
  ACCR(pp0, a0, ii) ACCR(pp1, a1, ii) ACCR(pp2, a2, ii) ACCR(pp3, a3, ii) }

#define BFLY(v) { v.x += __shfl_xor(v.x, off); v.y += __shfl_xor(v.y, off); \
                  v.z += __shfl_xor(v.z, off); v.w += __shfl_xor(v.w, off); }

#define W2CUPD(ii) { \
  float4 u0 = make_float4(0,0,0,0), u1 = u0, u2 = u0, u3 = u0; \
  const float* ab = abuf + (ii) * 2048 + 4 * tid; \
  _Pragma("unroll 4") \
  for (int r = 0; r < R; r++) { \
    float4 a4 = *(const float4*)&ab[(long)r * 4096]; \
    float4 g4 = *(const float4*)&gc[r * 4]; \
    u0.x += a4.x*g4.x; u0.y += a4.x*g4.y; u0.z += a4.x*g4.z; u0.w += a4.x*g4.w; \
    u1.x += a4.y*g4.x; u1.y += a4.y*g4.y; u1.z += a4.y*g4.z; u1.w += a4.y*g4.w; \
    u2.x += a4.z*g4.x; u2.y += a4.z*g4.y; u2.z += a4.z*g4.z; u2.w += a4.z*g4.w; \
    u3.x += a4.w*g4.x; u3.y += a4.w*g4.y; u3.z += a4.w*g4.z; u3.w += a4.w*g4.w; } \
  w2c[ii][0].x -= LR*u0.x; w2c[ii][0].y -= LR*u0.y; w2c[ii][0].z -= LR*u0.z; w2c[ii][0].w -= LR*u0.w; \
  w2c[ii][1].x -= LR*u1.x; w2c[ii][1].y -= LR*u1.y; w2c[ii][1].z -= LR*u1.z; w2c[ii][1].w -= LR*u1.w; \
  w2c[ii][2].x -= LR*u2.x; w2c[ii][2].y -= LR*u2.y; w2c[ii][2].z -= LR*u2.z; w2c[ii][2].w -= LR*u2.w; \
  w2c[ii][3].x -= LR*u3.x; w2c[ii][3].y -= LR*u3.y; w2c[ii][3].z -= LR*u3.z; w2c[ii][3].w -= LR*u3.w; }

// staging index helpers (2 float4 per thread per panel: R*PAN/2048 == 2)
#define STG_IDX(qi, rr, kk4) \
  const int rr = (qi) / (PAN / 4); const int kk4 = ((qi) % (PAN / 4)) * 4;

template<int P, int NC>
__global__ __launch_bounds__(512, 1) void ttt_fused(
    const float* __restrict__ lin, const float* __restrict__ dlt,
    float* __restrict__ W1, float* __restrict__ b1,
    float* __restrict__ W2, float* __restrict__ b2,
    float* __restrict__ abuf, float* __restrict__ Gbuf, int* __restrict__ bar)
{
  constexpr int R = 2 * P;             // rows per chunk (both batches)
  constexpr int RPT = R / 32;          // rows per thread in p1/p3
  constexpr float GS = 2.f / (float)R;
  constexpr float LR = 1e-3f;
  constexpr int PAN = (P == 16) ? 128 : 32;   // staged K/D panel width
  constexpr int PS  = PAN + 4;                // panel stride
  constexpr int ST = R + 4;
  // LDS layout (floats)
  constexpr int O_W2R = 16384;
  constexpr int O_SCR = O_W2R + 16 * 1028;
  constexpr int SCRSZ = R * PS;
  constexpr int O_ATD = O_SCR + SCRSZ;
  constexpr int O_GC  = O_ATD + 16 * ST;
  constexpr int O_B   = O_GC + R * 4;
  constexpr int SMTOT = O_B + 24;  // fast: 151,136 B; slow: 160,352 B

  __shared__ float smem[SMTOT];
  float* w1s  = smem;                // [1024][16] W1 own cols
  float* w2rs = smem + O_W2R;        // [16][1028] W2 own rows
  float* scr  = smem + O_SCR;        // [R][PS] staging / [8][R*4] partials
  float* atd  = smem + O_ATD;        // [16][ST] a^T then dZ^T (own cols)
  float* gc   = smem + O_GC;         // [R][4] G own cols
  float* b1s  = smem + O_B;          // [16]
  float* b2s  = smem + O_B + 16;     // [4]

  const int bid = blockIdx.x, tid = threadIdx.x;
  const int j0 = bid * 16, c0 = bid * 4;
  const int rg = tid >> 4, jj = tid & 15;
  const int jB = tid >> 5, dB = tid & 31;      // p3-B roles
  const int kkA = tid >> 4, jjA = tid & 15;    // p4a roles
  const int NB = gridDim.x;
  int ep = 0;

  // ---- init: resident weight slices (only global weight reads) ----
  for (int q = tid; q < 16384; q += 512) {
    int k = q >> 4, j = q & 15;
    w1s[k * 16 + j] = W1[(long)k * 4096 + j0 + j];
  }
  for (int q = tid; q < 16384; q += 512) {
    int j = q >> 10, d = q & 1023;
    w2rs[j * 1028 + d] = W2[(long)(j0 + j) * 1024 + d];
  }
  float4 w2c[2][4];
  #pragma unroll
  for (int i = 0; i < 2; i++)
    #pragma unroll
    for (int e = 0; e < 4; e++)
      w2c[i][e] = *(const float4*)&W2[(long)(i * 2048 + 4 * tid + e) * 1024 + c0];
  if (tid < 16) b1s[tid] = b1[j0 + tid];
  if (tid < 4)  b2s[tid] = b2[c0 + tid];
  __syncthreads();

  for (int c = 0; c < NC; c++) {
    const int rb0 = c * P, rb1 = 2048 - P + c * P;
    float zf[RPT];
    // ---------------- p1: z = ci@W1 + b1 ; a = gelu(z) -> atd, abuf ------
    {
      float zacc[RPT];
      #pragma unroll
      for (int i = 0; i < RPT; i++) zacc[i] = 0.f;
      STG_IDX(tid, r0, k40) STG_IDX(tid + 512, r1, k41)
      const long g0 = (r0 < P) ? (long)(rb0 + r0) : (long)(rb1 + r0);
      const long g1 = (r1 < P) ? (long)(rb0 + r1) : (long)(rb1 + r1);
      float4 pf0 = *(const float4*)&lin[g0 * 1024 + k40];
      float4 pf1 = *(const float4*)&lin[g1 * 1024 + k41];
      for (int kp = 0; kp < 1024; kp += PAN) {
        __syncthreads();                       // prior readers of scr done
        *(float4*)&scr[r0 * PS + k40] = pf0;
        *(float4*)&scr[r1 * PS + k41] = pf1;
        if (kp + PAN < 1024) {                 // issue-early next panel
          pf0 = *(const float4*)&lin[g0 * 1024 + kp + PAN + k40];
          pf1 = *(const float4*)&lin[g1 * 1024 + kp + PAN + k41];
        }
        __syncthreads();                       // scr ready
        #pragma unroll 8
        for (int k4 = 0; k4 < PAN / 4; k4++) {
          const float w0  = w1s[(kp + k4 * 4 + 0) * 16 + jj];
          const float w1v = w1s[(kp + k4 * 4 + 1) * 16 + jj];
          const float w2v = w1s[(kp + k4 * 4 + 2) * 16 + jj];
          const float w3v = w1s[(kp + k4 * 4 + 3) * 16 + jj];
          #pragma unroll
          for (int i = 0; i < RPT; i++) {
            const float4 c4 = *(const float4*)&scr[(rg * RPT + i) * PS + k4 * 4];
            zacc[i] += c4.x * w0 + c4.y * w1v + c4.z * w2v + c4.w * w3v;
          }
        }
      }
      const float b1v = b1s[jj];
      #pragma unroll
      for (int i = 0; i < RPT; i++) {
        const int r = rg * RPT + i;
        zf[i] = zacc[i] + b1v;
        const float a = gelu_f(zf[i]);
        atd[jj * ST + r] = a;
        st_coh(&abuf[(long)r * 4096 + j0 + jj], a);
      }
    }
    ++ep; grid_bar(bar, ep * NB);
    __builtin_amdgcn_fence(__ATOMIC_ACQUIRE, "agent");  // inv: fresh abuf
    // ------- p2: pred = a@W2 + b2 for own 4 cols (W2 cols in regs) -------
    {
      for (int g = 0; g < R / 4; g++) {
        float4 pp0 = make_float4(0,0,0,0), pp1 = pp0, pp2 = pp0, pp3 = pp0;
        P2ACC(0)
        P2ACC(1)
        #pragma unroll
        for (int off = 1; off < 64; off <<= 1) { BFLY(pp0) BFLY(pp1) BFLY(pp2) BFLY(pp3) }
        if ((tid & 63) == 0) {
          const int wv = tid >> 6;
          float* dst = &scr[wv * (R * 4) + g * 16];
          *(float4*)&dst[0]  = pp0;  *(float4*)&dst[4]  = pp1;
          *(float4*)&dst[8]  = pp2;  *(float4*)&dst[12] = pp3;
        }
      }
      __syncthreads();
      if (tid < R * 4) {
        const int r = tid >> 2, cc = tid & 3;
        float s = 0.f;
        #pragma unroll
        for (int wv = 0; wv < 8; wv++) s += scr[wv * (R * 4) + tid];
        const long grow = (r < P) ? (long)(rb0 + r) : (long)(rb1 + r);
        const int col = c0 + cc;
        const float tgt = lin[grow * 1024 + col]
                        + dlt[(long)(2 * c + (r >= P ? 1 : 0)) * 1024 + col];
        const float Gv = GS * (s + b2s[cc] - tgt);
        st_coh(&Gbuf[(long)r * 1024 + col], Gv);
        gc[tid] = Gv;
      }
      __syncthreads();
      if (tid < 4) {
        float s = 0.f;
        for (int r = 0; r < R; r++) s += gc[r * 4 + tid];
        b2s[tid] -= LR * s;
      }
      // register W2-col update from L2-hot abuf + gc
      W2CUPD(0)
      W2CUPD(1)
    }
    ++ep; grid_bar(bar, ep * NB);
    __builtin_amdgcn_fence(__ATOMIC_ACQUIRE, "agent");  // inv: fresh Gbuf
    // ---------------- p3: dZ = (G@W2^T)*gelu'(z); w2rs row update --------
    {
      float dzacc[RPT];
      #pragma unroll
      for (int i = 0; i < RPT; i++) dzacc[i] = 0.f;
      STG_IDX(tid, r0, d40) STG_IDX(tid + 512, r1, d41)
      float4 pg0 = *(const float4*)&Gbuf[(long)r0 * 1024 + d40];
      float4 pg1 = *(const float4*)&Gbuf[(long)r1 * 1024 + d41];
      for (int dp = 0; dp < 1024; dp += PAN) {
        __syncthreads();                       // prior readers of scr done
        *(float4*)&scr[r0 * PS + d40] = pg0;
        *(float4*)&scr[r1 * PS + d41] = pg1;
        if (dp + PAN < 1024) {
          pg0 = *(const float4*)&Gbuf[(long)r0 * 1024 + dp + PAN + d40];
          pg1 = *(const float4*)&Gbuf[(long)r1 * 1024 + dp + PAN + d41];
        }
        __syncthreads();                       // scr ready
        // A: dZ partial (PRE-update W2 rows from LDS)
        #pragma unroll 8
        for (int d4 = 0; d4 < PAN / 4; d4++) {
          const float4 w4 = *(const float4*)&w2rs[jj * 1028 + dp + d4 * 4];
          #pragma unroll
          for (int i = 0; i < RPT; i++) {
            const float4 g4 = *(const float4*)&scr[(rg * RPT + i) * PS + d4 * 4];
            dzacc[i] += g4.x * w4.x + g4.y * w4.y + g4.z * w4.z + g4.w * w4.w;
          }
        }
        __syncthreads();   // A must finish before B writes w2rs
        // B: W2 row-panel rank-R update (LDS only; global write at end)
        #pragma unroll
        for (int t = 0; t < PAN / 32; t++) {
          const int d = dB + t * 32;
          float s = 0.f;
          #pragma unroll 4
          for (int r = 0; r < R; r++) s += atd[jB * ST + r] * scr[r * PS + d];
          w2rs[jB * 1028 + dp + d] -= LR * s;
        }
      }
      __syncthreads();       // B done before atd is overwritten with dZ^T
      float bsum = 0.f;
      #pragma unroll
      for (int i = 0; i < RPT; i++) {
        const int r = rg * RPT + i;
        const float dz = dzacc[i] * gelu_grad_f(zf[i]);
        atd[jj * ST + r] = dz;
        bsum += dz;
      }
      scr[tid] = bsum;
      __syncthreads();
      if (tid < 16) {
        float s = 0.f;
        #pragma unroll
        for (int g2 = 0; g2 < 32; g2++) s += scr[g2 * 16 + tid];
        b1s[tid] -= LR * s;
      }
      __syncthreads();
    }
    // ---------------- p4a: W1 own-col update (LDS-resident) --------------
    {
      STG_IDX(tid, r0, k40) STG_IDX(tid + 512, r1, k41)
      const long g0 = (r0 < P) ? (long)(rb0 + r0) : (long)(rb1 + r0);
      const long g1 = (r1 < P) ? (long)(rb0 + r1) : (long)(rb1 + r1);
      float4 pc0 = *(const float4*)&lin[g0 * 1024 + k40];
      float4 pc1 = *(const float4*)&lin[g1 * 1024 + k41];
      for (int kp = 0; kp < 1024; kp += PAN) {
        __syncthreads();
        *(float4*)&scr[r0 * PS + k40] = pc0;
        *(float4*)&scr[r1 * PS + k41] = pc1;
        if (kp + PAN < 1024) {
          pc0 = *(const float4*)&lin[g0 * 1024 + kp + PAN + k40];
          pc1 = *(const float4*)&lin[g1 * 1024 + kp + PAN + k41];
        }
        __syncthreads();
        #pragma unroll
        for (int t = 0; t < PAN / 32; t++) {
          const int kl = kkA + t * 32;
          float s = 0.f;
          #pragma unroll 4
          for (int r4 = 0; r4 < R; r4 += 4) {
            const float4 d4 = *(const float4*)&atd[jjA * ST + r4];
            s += scr[(r4 + 0) * PS + kl] * d4.x + scr[(r4 + 1) * PS + kl] * d4.y
               + scr[(r4 + 2) * PS + kl] * d4.z + scr[(r4 + 3) * PS + kl] * d4.w;
          }
          w1s[(kp + kl) * 16 + jjA] -= LR * s;
        }
      }
    }
    // no grid barrier at chunk end: next p1's first scr store is behind a
    // __syncthreads; cross-block consumers are all behind the next BAR1
  }

  // ---- final writeback of all resident state ----
  __syncthreads();
  for (int q = tid; q < 16384; q += 512) {
    int k = q >> 4, j = q & 15;
    W1[(long)k * 4096 + j0 + j] = w1s[k * 16 + j];
  }
  for (int q = tid; q < 16384; q += 512) {
    int j = q >> 10, d = q & 1023;
    W2[(long)(j0 + j) * 1024 + d] = w2rs[j * 1028 + d];
  }
  if (tid < 16) b1[j0 + tid] = b1s[tid];
  if (tid < 4)  b2[c0 + tid] = b2s[tid];
}

extern "C" void kernel_launch(void* const* d_in, const int* in_sizes, int n_in,
                              void* d_out, int out_size, void* d_ws, size_t ws_size,
                              hipStream_t stream) {
  const float* x     = (const float*)d_in[0];
  const float* teach = (const float*)d_in[1];
  const float* wq    = (const float*)d_in[2];
  const float* wk    = (const float*)d_in[3];
  const float* wv    = (const float*)d_in[4];
  const float* wo    = (const float*)d_in[5];
  float* out = (float*)d_out;
  float* ws  = (float*)d_ws;

  // ---- d_out layout (floats): cms_out, then the 8 updated params ----
  const long P_W1F = 4194304;
  const long P_B1F = 8388608;
  const long P_W2F = 8392704;
  const long P_B2F = 12587008;
  const long P_W1S = 12588032;
  const long P_B1S = 16782336;
  const long P_W2S = 16786432;
  const long P_B2S = 20980736;

  // ---- ws layout (floats) ----
  const long O_Q   = 0;
  const long O_K   = 4194304;
  const long O_V   = 8388608;
  const long O_CTX = 12582912;
  const long O_H   = 0;          // MLP hidden [4096,4096] (fwd; overlays QKV/CTX)
  const long O_AB  = 0;          // TTT abuf [R,4096]
  const long O_GB  = 524288;     // TTT Gbuf [R,1024]
  const long O_BAR = 12582912;   // TTT grid-barrier counters (dead CTX region)
  const long O_INF = 16787456;   // in_fast [4096,1024]
  const long O_INS = 20981760;   // in_slow [4096,1024]
  const long O_DF  = 25176064;   // 262,144
  const long O_DS  = 25438208;   // 65,536

  // --- seed fp32 masters directly into d_out (updated in place by TTT) ---
  {
    const long poff[8] = {P_W1F, P_B1F, P_W2F, P_B2F, P_W1S, P_B1S, P_W2S, P_B2S};
    const size_t psz[8] = {4194304, 4096, 4194304, 1024, 4194304, 4096, 4194304, 1024};
    for (int i = 0; i < 8; i++)
      hipMemcpyAsync(out + poff[i], d_in[6 + i], psz[i] * sizeof(float),
                     hipMemcpyDeviceToDevice, stream);
  }

  // --- per-chunk teach means ---
  compute_deltas<<<dim3(1281), 256, 0, stream>>>(teach, ws + O_DF, ws + O_DS);

  // --- Q/K/V projections ---
  {
    dim3 grd(16, 64);
    gemm_k<false, 0><<<grd, 256, 0, stream>>>(
        x, wq, ws + O_Q, nullptr, nullptr, 4096, 1024, 1024, 1024, 1024,
        4096, 0, 0, nullptr, 1, 0, 0, nullptr, 0.f);
    gemm_k<false, 0><<<grd, 256, 0, stream>>>(
        x, wk, ws + O_K, nullptr, nullptr, 4096, 1024, 1024, 1024, 1024,
        4096, 0, 0, nullptr, 1, 0, 0, nullptr, 0.f);
    gemm_k<false, 0><<<grd, 256, 0, stream>>>(
        x, wv, ws + O_V, nullptr, nullptr, 4096, 1024, 1024, 1024, 1024,
        4096, 0, 0, nullptr, 1, 0, 0, nullptr, 0.f);
  }

  // --- causal attention ---
  attn_kernel<<<dim3(32, 16, 2), 256, 0, stream>>>(ws + O_Q, ws + O_K, ws + O_V, ws + O_CTX);

  // --- in_fast = ctx @ wo ---
  gemm_k<false, 0><<<dim3(16, 64), 256, 0, stream>>>(
      ws + O_CTX, wo, ws + O_INF, nullptr, nullptr, 4096, 1024, 1024, 1024, 1024,
      4096, 0, 0, nullptr, 1, 0, 0, nullptr, 0.f);

  // --- MLP forwards with BASE params; full-width hidden buffer ---
  gemm_k<false, 1><<<dim3(64, 64), 256, 0, stream>>>(
      ws + O_INF, out + P_W1F, ws + O_H, nullptr, out + P_B1F,
      4096, 4096, 1024, 1024, 4096, 4096, 0, 0, nullptr, 1, 0, 0, nullptr, 0.f);
  gemm_k<false, 0><<<dim3(16, 64), 256, 0, stream>>>(
      ws + O_H, out + P_W2F, ws + O_INS, nullptr, out + P_B2F,
      4096, 1024, 4096, 4096, 1024, 4096, 0, 0, nullptr, 1, 0, 0, nullptr, 0.f);
  gemm_k<false, 1><<<dim3(64, 64), 256, 0, stream>>>(
      ws + O_INS, out + P_W1S, ws + O_H, nullptr, out + P_B1S,
      4096, 4096, 1024, 1024, 4096, 4096, 0, 0, nullptr, 1, 0, 0, nullptr, 0.f);
  gemm_k<false, 0><<<dim3(16, 64), 256, 0, stream>>>(
      ws + O_H, out + P_W2S, out, nullptr, out + P_B2S,
      4096, 1024, 4096, 4096, 1024, 4096, 0, 0, nullptr, 1, 0, 0, nullptr, 0.f);

  // --- TTT updates: ONE persistent kernel per level, weights on-chip ---
  hipMemsetAsync(ws + O_BAR, 0, 1024, stream);
  ttt_fused<16, 128><<<dim3(256), dim3(512), 0, stream>>>(
      ws + O_INF, ws + O_DF, out + P_W1F, out + P_B1F, out + P_W2F, out + P_B2F,
      ws + O_AB, ws + O_GB, (int*)(ws + O_BAR));
  hipMemsetAsync(ws + O_BAR, 0, 1024, stream);
  ttt_fused<64, 32><<<dim3(256), dim3(512), 0, stream>>>(
      ws + O_INS, ws + O_DS, out + P_W1S, out + P_B1S, out + P_W2S, out + P_B2S,
      ws + O_AB, ws + O_GB, (int*)(ws + O_BAR));
}

// Round 7
// 32125.107 us; speedup vs baseline: 1.2547x; 1.0844x over previous
//
#include <hip/hip_runtime.h>
#include <hip/hip_bf16.h>

// tanh-approx GELU (JAX default) and its exact derivative
__device__ __forceinline__ float gelu_f(float x) {
  const float c = 0.7978845608028654f;
  float u = c * (x + 0.044715f * x * x * x);
  float t = tanhf(u);
  return 0.5f * x * (1.f + t);
}
__device__ __forceinline__ float gelu_grad_f(float x) {
  const float c = 0.7978845608028654f;
  float x2 = x * x;
  float u = c * (x + 0.044715f * x2 * x);
  float t = tanhf(u);
  return 0.5f * (1.f + t) + 0.5f * x * (1.f - t * t) * c * (1.f + 0.134145f * x2);
}

// Agent-scope coherent (sc1) publish path for cross-block producer->consumer
// buffers. Consumers read PLAIN (L2-cached) after a per-phase acquire fence.
__device__ __forceinline__ void st_coh(float* p, float v) {
  __hip_atomic_store(p, v, __ATOMIC_RELAXED, __HIP_MEMORY_SCOPE_AGENT);
}

// ---------------------------------------------------------------------------
// Tiled fp32 GEMM (forward path). 64x64 tile, 16-deep K panel.
// ---------------------------------------------------------------------------
template<bool TRANSB, int ACT>
__global__ __launch_bounds__(256) void gemm_k(
    const float* __restrict__ A, const float* __restrict__ B, float* __restrict__ C,
    float* __restrict__ Zbuf, const float* __restrict__ bias,
    int M, int N, int K, int lda, int ldb,
    int P, int bsRows, int rowOff,
    const float* __restrict__ ci, int ciP, int ciBs, int ciOff,
    const float* __restrict__ delta, float gscale)
{
  __shared__ float As[16][68];
  __shared__ float Bs[16][68];
  const int bm = blockIdx.y * 64, bn = blockIdx.x * 64;
  const int tid = threadIdx.x;
  const int tr = tid >> 4, tc = tid & 15;
  float acc[4][4] = {};
  for (int k0 = 0; k0 < K; k0 += 16) {
    {
      const int e = tid * 4;
      const int m = e >> 4, kk = e & 15;
      const int gm = bm + m;
      const bool mv = gm < M;
      const long grow = (long)(gm / P) * bsRows + rowOff + (gm % P);
      const float* ap = A + grow * lda + k0 + kk;
      #pragma unroll
      for (int i = 0; i < 4; i++) {
        float v = 0.f;
        if (mv) v = ap[i];
        As[kk + i][m] = v;
      }
    }
    if (!TRANSB) {
      const int e = tid * 4;
      const int kk = e >> 6, n = e & 63;
      const int gn = bn + n;
      const float* bp = B + (long)(k0 + kk) * ldb + gn;
      #pragma unroll
      for (int i = 0; i < 4; i++) Bs[kk][n + i] = bp[i];
    } else {
      const int e = tid * 4;
      const int n = e >> 4, kk = e & 15;
      const int gn = bn + n;
      const float* bp = B + (long)gn * ldb + k0 + kk;
      #pragma unroll
      for (int i = 0; i < 4; i++) Bs[kk + i][n] = bp[i];
    }
    __syncthreads();
    #pragma unroll
    for (int kk = 0; kk < 16; kk++) {
      float a[4], b[4];
      #pragma unroll
      for (int i = 0; i < 4; i++) a[i] = As[kk][tr * 4 + i];
      #pragma unroll
      for (int j = 0; j < 4; j++) b[j] = Bs[kk][tc * 4 + j];
      #pragma unroll
      for (int i = 0; i < 4; i++)
        #pragma unroll
        for (int j = 0; j < 4; j++) acc[i][j] += a[i] * b[j];
    }
    __syncthreads();
  }
  #pragma unroll
  for (int i = 0; i < 4; i++) {
    const int m = bm + tr * 4 + i;
    if (m >= M) continue;
    #pragma unroll
    for (int j = 0; j < 4; j++) {
      const int n = bn + tc * 4 + j;
      if (n >= N) continue;
      float v = acc[i][j];
      if (bias) v += bias[n];
      if (ACT == 1) {
        if (Zbuf) Zbuf[(long)m * N + n] = v;
        v = gelu_f(v);
      } else if (ACT == 2) {
        const long crow = (long)(m / ciP) * ciBs + ciOff + (m % ciP);
        const float tgt = ci[crow * 1024 + n] + delta[(m / ciP) * 1024 + n];
        v = gscale * (v - tgt);
      } else if (ACT == 3) {
        v = v * gelu_grad_f(Zbuf[(long)m * N + n]);
      }
      C[(long)m * N + n] = v;
    }
  }
}

// ---------------------------------------------------------------------------
// Flash-style causal attention. q-tiles launched longest-first (tail balance).
// ---------------------------------------------------------------------------
__global__ __launch_bounds__(256) void attn_kernel(
    const float* __restrict__ Q, const float* __restrict__ K,
    const float* __restrict__ V, float* __restrict__ ctx)
{
  const int S = 2048, D = 1024;
  const int qt = (int)gridDim.x - 1 - (int)blockIdx.x;  // longest blocks first
  const int h = blockIdx.y, b = blockIdx.z;
  const int q0 = qt * 64;
  __shared__ float Qs[64][65];
  __shared__ float Ks[32][65];
  __shared__ float Vs[32][65];
  __shared__ float Ss[64][33];
  const int tid = threadIdx.x;
  for (int e = tid; e < 4096; e += 256) {
    int r = e >> 6, d = e & 63;
    Qs[r][d] = Q[(long)(b * S + q0 + r) * D + h * 64 + d];
  }
  const int r = tid >> 2;
  const int g = tid & 3;
  const int dg8 = g * 8;
  const int dg16 = g * 16;
  float acc[16];
  #pragma unroll
  for (int i = 0; i < 16; i++) acc[i] = 0.f;
  float mrow = -1e30f, lrow = 0.f;
  for (int k0 = 0; k0 < q0 + 64; k0 += 32) {
    __syncthreads();
    for (int e = tid; e < 2048; e += 256) {
      int rr = e >> 6, d = e & 63;
      Ks[rr][d] = K[(long)(b * S + k0 + rr) * D + h * 64 + d];
      Vs[rr][d] = V[(long)(b * S + k0 + rr) * D + h * 64 + d];
    }
    __syncthreads();
    float sc[8];
    #pragma unroll
    for (int j = 0; j < 8; j++) sc[j] = 0.f;
    for (int d = 0; d < 64; d++) {
      float qd = Qs[r][d];
      #pragma unroll
      for (int j = 0; j < 8; j++) sc[j] += qd * Ks[dg8 + j][d];
    }
    float tmax = -1e30f;
    #pragma unroll
    for (int j = 0; j < 8; j++) {
      sc[j] *= 0.125f;
      if (k0 + dg8 + j > q0 + r) sc[j] = -1e30f;
      tmax = fmaxf(tmax, sc[j]);
    }
    tmax = fmaxf(tmax, __shfl_xor(tmax, 1));
    tmax = fmaxf(tmax, __shfl_xor(tmax, 2));
    const float newm = fmaxf(mrow, tmax);
    const float scale = __expf(mrow - newm);
    float psum = 0.f;
    #pragma unroll
    for (int j = 0; j < 8; j++) {
      sc[j] = __expf(sc[j] - newm);
      psum += sc[j];
    }
    psum += __shfl_xor(psum, 1);
    psum += __shfl_xor(psum, 2);
    lrow = lrow * scale + psum;
    mrow = newm;
    #pragma unroll
    for (int i = 0; i < 16; i++) acc[i] *= scale;
    #pragma unroll
    for (int j = 0; j < 8; j++) Ss[r][dg8 + j] = sc[j];
    __syncthreads();
    for (int c = 0; c < 32; c++) {
      float p = Ss[r][c];
      #pragma unroll
      for (int i = 0; i < 16; i++) acc[i] += p * Vs[c][dg16 + i];
    }
  }
  const float inv = 1.f / lrow;
  #pragma unroll
  for (int i = 0; i < 16; i++)
    ctx[(long)(b * S + q0 + r) * D + h * 64 + dg16 + i] = acc[i] * inv;
}

// Per-chunk teach means for both levels (unchanged).
__global__ void compute_deltas(const float* __restrict__ teach,
                               float* __restrict__ dF, float* __restrict__ dS)
{
  const int nF = 128 * 2048;
  const int nS = 32 * 2048;
  int t = blockIdx.x * blockDim.x + threadIdx.x;
  if (t < nF) {
    int c = t >> 11, b = (t >> 10) & 1, d = t & 1023;
    long base = ((long)(b * 2048 + c * 16)) * 1024 + d;
    float s = 0.f;
    for (int k = 0; k < 16; k++) s += teach[base + (long)k * 1024];
    dF[t] = s * (1.f / 16.f);
  } else if (t < nF + nS) {
    int u = t - nF;
    int c = u >> 11, b = (u >> 10) & 1, d = u & 1023;
    long base = ((long)(b * 2048 + c * 64)) * 1024 + d;
    float s = 0.f;
    for (int k = 0; k < 64; k++) s += teach[base + (long)k * 1024];
    dS[u] = s * (1.f / 64.f);
  }
}

// ---------------------------------------------------------------------------
// Grid barrier: relaxed agent atomics, 8 padded counters.
// ---------------------------------------------------------------------------
__device__ __forceinline__ void grid_bar(int* cnt, int target) {
  __syncthreads();
  if (threadIdx.x == 0) {
    __hip_atomic_fetch_add(&cnt[(blockIdx.x & 7) * 32], 1,
                           __ATOMIC_RELAXED, __HIP_MEMORY_SCOPE_AGENT);
    int spins = 0;
    for (;;) {
      int s = 0;
      #pragma unroll
      for (int i = 0; i < 8; i++)
        s += __hip_atomic_load(&cnt[i * 32], __ATOMIC_RELAXED, __HIP_MEMORY_SCOPE_AGENT);
      if (s >= target) break;
      __builtin_amdgcn_s_sleep(2);
      if (++spins > (1 << 20)) break;   // bailout: corrupt, don't hang
    }
  }
  __syncthreads();
}

// ---------------------------------------------------------------------------
// Fused TTT scan, fully on-chip weights (round-5 ownership, proven correct).
// Round-7: p1/p3/p4a use DIRECT global reads (wave-broadcast within a row
// group, L2-dedup across blocks) instead of LDS panel staging -> syncs/chunk
// ~200 -> ~12, loads overlap freely instead of lockstep panel round-trips.
// ---------------------------------------------------------------------------
#define ACCR(pp, a, ii) \
  pp.x += a.x*w2c[ii][0].x + a.y*w2c[ii][1].x + a.z*w2c[ii][2].x + a.w*w2c[ii][3].x; \
  pp.y += a.x*w2c[ii][0].y + a.y*w2c[ii][1].y + a.z*w2c[ii][2].y + a.w*w2c[ii][3].y; \
  pp.z += a.x*w2c[ii][0].z + a.y*w2c[ii][1].z + a.z*w2c[ii][2].z + a.w*w2c[ii][3].z; \
  pp.w += a.x*w2c[ii][0].w + a.y*w2c[ii][1].w + a.z*w2c[ii][2].w + a.w*w2c[ii][3].w;

#define P2ACC(ii) { \
  const float* ab = abuf + (long)(g * 4) * 4096 + (ii) * 2048 + 4 * tid; \
  float4 a0 = *(const float4*)&ab[0]; \
  float4 a1 = *(const float4*)&ab[4096]; \
  float4 a2 = *(const float4*)&ab[8192]; \
  float4 a3 = *(const float4*)&ab[12288]; \
  ACCR(pp0, a0, ii) ACCR(pp1, a1, ii) ACCR(pp2, a2, ii) ACCR(pp3, a3, ii) }

#define BFLY(v) { v.x += __shfl_xor(v.x, off); v.y += __shfl_xor(v.y, off); \
                  v.z += __shfl_xor(v.z, off); v.w += __shfl_xor(v.w, off); }

#define W2CUPD(ii) { \
  float4 u0 = make_float4(0,0,0,0), u1 = u0, u2 = u0, u3 = u0; \
  const float* ab = abuf + (ii) * 2048 + 4 * tid; \
  _Pragma("unroll 4") \
  for (int r = 0; r < R; r++) { \
    float4 a4 = *(const float4*)&ab[(long)r * 4096]; \
    float4 g4 = *(const float4*)&gc[r * 4]; \
    u0.x += a4.x*g4.x; u0.y += a4.x*g4.y; u0.z += a4.x*g4.z; u0.w += a4.x*g4.w; \
    u1.x += a4.y*g4.x; u1.y += a4.y*g4.y; u1.z += a4.y*g4.z; u1.w += a4.y*g4.w; \
    u2.x += a4.z*g4.x; u2.y += a4.z*g4.y; u2.z += a4.z*g4.z; u2.w += a4.z*g4.w; \
    u3.x += a4.w*g4.x; u3.y += a4.w*g4.y; u3.z += a4.w*g4.z; u3.w += a4.w*g4.w; } \
  w2c[ii][0].x -= LR*u0.x; w2c[ii][0].y -= LR*u0.y; w2c[ii][0].z -= LR*u0.z; w2c[ii][0].w -= LR*u0.w; \
  w2c[ii][1].x -= LR*u1.x; w2c[ii][1].y -= LR*u1.y; w2c[ii][1].z -= LR*u1.z; w2c[ii][1].w -= LR*u1.w; \
  w2c[ii][2].x -= LR*u2.x; w2c[ii][2].y -= LR*u2.y; w2c[ii][2].z -= LR*u2.z; w2c[ii][2].w -= LR*u2.w; \
  w2c[ii][3].x -= LR*u3.x; w2c[ii][3].y -= LR*u3.y; w2c[ii][3].z -= LR*u3.z; w2c[ii][3].w -= LR*u3.w; }

template<int P, int NC>
__global__ __launch_bounds__(512, 1) void ttt_fused(
    const float* __restrict__ lin, const float* __restrict__ dlt,
    float* __restrict__ W1, float* __restrict__ b1,
    float* __restrict__ W2, float* __restrict__ b2,
    float* __restrict__ abuf, float* __restrict__ Gbuf, int* __restrict__ bar)
{
  constexpr int R = 2 * P;             // rows per chunk (both batches)
  constexpr int RPT = R / 32;          // rows per thread in p1/p3
  constexpr float GS = 2.f / (float)R;
  constexpr float LR = 1e-3f;
  constexpr int ST = R + 4;
  // LDS layout (floats)
  constexpr int O_W2R = 16384;
  constexpr int O_SCR = O_W2R + 16 * 1028;
  constexpr int SCRSZ = (8 * R * 4 > 512) ? 8 * R * 4 : 512;  // p2 partials / bsum
  constexpr int O_ATD = O_SCR + SCRSZ;
  constexpr int O_GC  = O_ATD + 16 * ST;
  constexpr int O_B   = O_GC + R * 4;
  constexpr int SMTOT = O_B + 24;  // fast: 138,336 B; slow: 158,304 B

  __shared__ float smem[SMTOT];
  float* w1s  = smem;                // [1024][16] W1 own cols
  float* w2rs = smem + O_W2R;        // [16][1028] W2 own rows
  float* scr  = smem + O_SCR;        // [8][R*4] p2 partials / [512] bsum
  float* atd  = smem + O_ATD;        // [16][ST] a^T then dZ^T (own cols)
  float* gc   = smem + O_GC;         // [R][4] G own cols
  float* b1s  = smem + O_B;          // [16]
  float* b2s  = smem + O_B + 16;     // [4]

  const int bid = blockIdx.x, tid = threadIdx.x;
  const int j0 = bid * 16, c0 = bid * 4;
  const int rg = tid >> 4, jj = tid & 15;
  const int jB = tid >> 5, dB = tid & 31;      // p3-B roles
  const int kkA = tid >> 4, jjA = tid & 15;    // p4a roles
  const int NB = gridDim.x;
  int ep = 0;

  // ---- init: resident weight slices (only global weight reads) ----
  for (int q = tid; q < 16384; q += 512) {
    int k = q >> 4, j = q & 15;
    w1s[k * 16 + j] = W1[(long)k * 4096 + j0 + j];
  }
  for (int q = tid; q < 16384; q += 512) {
    int j = q >> 10, d = q & 1023;
    w2rs[j * 1028 + d] = W2[(long)(j0 + j) * 1024 + d];
  }
  float4 w2c[2][4];
  #pragma unroll
  for (int i = 0; i < 2; i++)
    #pragma unroll
    for (int e = 0; e < 4; e++)
      w2c[i][e] = *(const float4*)&W2[(long)(i * 2048 + 4 * tid + e) * 1024 + c0];
  if (tid < 16) b1s[tid] = b1[j0 + tid];
  if (tid < 4)  b2s[tid] = b2[c0 + tid];
  __syncthreads();

  for (int c = 0; c < NC; c++) {
    const int rb0 = c * P, rb1 = 2048 - P + c * P;
    long grows[RPT];
    #pragma unroll
    for (int i = 0; i < RPT; i++) {
      const int r = rg * RPT + i;
      grows[i] = (r < P) ? (long)(rb0 + r) : (long)(rb1 + r);
    }
    float zf[RPT];
    // ---- p1: z = ci@W1 + b1 ; a = gelu(z) -> atd, abuf. Direct reads,
    //      wave-broadcast across the 16 jj lanes of a row group. NO syncs. ----
    {
      float zacc[RPT];
      #pragma unroll
      for (int i = 0; i < RPT; i++) zacc[i] = 0.f;
      #pragma unroll 4
      for (int k4 = 0; k4 < 256; k4++) {
        const int k = k4 * 4;
        const float w0  = w1s[(k + 0) * 16 + jj];
        const float w1v = w1s[(k + 1) * 16 + jj];
        const float w2v = w1s[(k + 2) * 16 + jj];
        const float w3v = w1s[(k + 3) * 16 + jj];
        #pragma unroll
        for (int i = 0; i < RPT; i++) {
          const float4 c4 = *(const float4*)&lin[grows[i] * 1024 + k];
          zacc[i] += c4.x * w0 + c4.y * w1v + c4.z * w2v + c4.w * w3v;
        }
      }
      const float b1v = b1s[jj];
      #pragma unroll
      for (int i = 0; i < RPT; i++) {
        const int r = rg * RPT + i;
        zf[i] = zacc[i] + b1v;
        const float a = gelu_f(zf[i]);
        atd[jj * ST + r] = a;
        st_coh(&abuf[(long)r * 4096 + j0 + jj], a);
      }
    }
    ++ep; grid_bar(bar, ep * NB);
    __builtin_amdgcn_fence(__ATOMIC_ACQUIRE, "agent");  // inv: fresh abuf
    // ------- p2: pred = a@W2 + b2 for own 4 cols (W2 cols in regs) -------
    {
      for (int g = 0; g < R / 4; g++) {
        float4 pp0 = make_float4(0,0,0,0), pp1 = pp0, pp2 = pp0, pp3 = pp0;
        P2ACC(0)
        P2ACC(1)
        #pragma unroll
        for (int off = 1; off < 64; off <<= 1) { BFLY(pp0) BFLY(pp1) BFLY(pp2) BFLY(pp3) }
        if ((tid & 63) == 0) {
          const int wv = tid >> 6;
          float* dst = &scr[wv * (R * 4) + g * 16];
          *(float4*)&dst[0]  = pp0;  *(float4*)&dst[4]  = pp1;
          *(float4*)&dst[8]  = pp2;  *(float4*)&dst[12] = pp3;
        }
      }
      __syncthreads();
      if (tid < R * 4) {
        const int r = tid >> 2, cc = tid & 3;
        float s = 0.f;
        #pragma unroll
        for (int wv = 0; wv < 8; wv++) s += scr[wv * (R * 4) + tid];
        const long grow = (r < P) ? (long)(rb0 + r) : (long)(rb1 + r);
        const int col = c0 + cc;
        const float tgt = lin[grow * 1024 + col]
                        + dlt[(long)(2 * c + (r >= P ? 1 : 0)) * 1024 + col];
        const float Gv = GS * (s + b2s[cc] - tgt);
        st_coh(&Gbuf[(long)r * 1024 + col], Gv);
        gc[tid] = Gv;
      }
      __syncthreads();
      if (tid < 4) {
        float s = 0.f;
        for (int r = 0; r < R; r++) s += gc[r * 4 + tid];
        b2s[tid] -= LR * s;
      }
      // register W2-col update from L2-hot abuf + gc
      W2CUPD(0)
      W2CUPD(1)
    }
    ++ep; grid_bar(bar, ep * NB);
    __builtin_amdgcn_fence(__ATOMIC_ACQUIRE, "agent");  // inv: fresh Gbuf
    // ---- p3-A: dZ = G @ W2^T (PRE-update rows). Direct G reads. ----
    float dzacc[RPT];
    {
      #pragma unroll
      for (int i = 0; i < RPT; i++) dzacc[i] = 0.f;
      #pragma unroll 4
      for (int d4 = 0; d4 < 256; d4++) {
        const int d = d4 * 4;
        const float4 w4 = *(const float4*)&w2rs[jj * 1028 + d];
        #pragma unroll
        for (int i = 0; i < RPT; i++) {
          const int r = rg * RPT + i;
          const float4 g4 = *(const float4*)&Gbuf[(long)r * 1024 + d];
          dzacc[i] += g4.x * w4.x + g4.y * w4.y + g4.z * w4.z + g4.w * w4.w;
        }
      }
    }
    __syncthreads();   // all A reads of w2rs done before B updates it
    // ---- p3-B: w2rs[j][:] -= LR * a[j,:]^T @ G. Direct G reads
    //      (coalesced 512B per wave, jB-broadcast). ----
    {
      #pragma unroll 2
      for (int t = 0; t < 8; t++) {
        const int d = (dB + 32 * t) * 4;
        float4 s = make_float4(0,0,0,0);
        #pragma unroll 4
        for (int r = 0; r < R; r++) {
          const float av = atd[jB * ST + r];
          const float4 g4 = *(const float4*)&Gbuf[(long)r * 1024 + d];
          s.x += av * g4.x; s.y += av * g4.y; s.z += av * g4.z; s.w += av * g4.w;
        }
        float4 wv = *(float4*)&w2rs[jB * 1028 + d];
        wv.x -= LR * s.x; wv.y -= LR * s.y; wv.z -= LR * s.z; wv.w -= LR * s.w;
        *(float4*)&w2rs[jB * 1028 + d] = wv;
      }
    }
    __syncthreads();   // B's atd reads done before dz overwrite
    // ---- p3 tail: dz = dzacc * gelu'(z) -> atd; b1 update ----
    {
      float bsum = 0.f;
      #pragma unroll
      for (int i = 0; i < RPT; i++) {
        const int r = rg * RPT + i;
        const float dz = dzacc[i] * gelu_grad_f(zf[i]);
        atd[jj * ST + r] = dz;
        bsum += dz;
      }
      scr[tid] = bsum;
      __syncthreads();
      if (tid < 16) {
        float s = 0.f;
        #pragma unroll
        for (int g2 = 0; g2 < 32; g2++) s += scr[g2 * 16 + tid];
        b1s[tid] -= LR * s;
      }
    }
    // ---- p4a: W1 own-col update. Direct ci reads (broadcast-16). ----
    {
      #pragma unroll 2
      for (int t = 0; t < 8; t++) {
        const int k = (kkA + 32 * t) * 4;
        float4 s = make_float4(0,0,0,0);
        #pragma unroll 4
        for (int r = 0; r < P; r++) {
          const float dzv = atd[jjA * ST + r];
          const float4 c4 = *(const float4*)&lin[(long)(rb0 + r) * 1024 + k];
          s.x += dzv * c4.x; s.y += dzv * c4.y; s.z += dzv * c4.z; s.w += dzv * c4.w;
        }
        #pragma unroll 4
        for (int r = P; r < R; r++) {
          const float dzv = atd[jjA * ST + r];
          const float4 c4 = *(const float4*)&lin[(long)(rb1 + r) * 1024 + k];
          s.x += dzv * c4.x; s.y += dzv * c4.y; s.z += dzv * c4.z; s.w += dzv * c4.w;
        }
        w1s[(k + 0) * 16 + jjA] -= LR * s.x;
        w1s[(k + 1) * 16 + jjA] -= LR * s.y;
        w1s[(k + 2) * 16 + jjA] -= LR * s.z;
        w1s[(k + 3) * 16 + jjA] -= LR * s.w;
      }
    }
    __syncthreads();   // w1s/atd/b1s stable before next chunk's p1
    // no grid barrier at chunk end (ownership; cross-block consumers are all
    // behind the next BAR1)
  }

  // ---- final writeback of all resident state ----
  for (int q = tid; q < 16384; q += 512) {
    int k = q >> 4, j = q & 15;
    W1[(long)k * 4096 + j0 + j] = w1s[k * 16 + j];
  }
  for (int q = tid; q < 16384; q += 512) {
    int j = q >> 10, d = q & 1023;
    W2[(long)(j0 + j) * 1024 + d] = w2rs[j * 1028 + d];
  }
  if (tid < 16) b1[j0 + tid] = b1s[tid];
  if (tid < 4)  b2[c0 + tid] = b2s[tid];
}

extern "C" void kernel_launch(void* const* d_in, const int* in_sizes, int n_in,
                              void* d_out, int out_size, void* d_ws, size_t ws_size,
                              hipStream_t stream) {
  const float* x     = (const float*)d_in[0];
  const float* teach = (const float*)d_in[1];
  const float* wq    = (const float*)d_in[2];
  const float* wk    = (const float*)d_in[3];
  const float* wv    = (const float*)d_in[4];
  const float* wo    = (const float*)d_in[5];
  float* out = (float*)d_out;
  float* ws  = (float*)d_ws;

  // ---- d_out layout (floats): cms_out, then the 8 updated params ----
  const long P_W1F = 4194304;
  const long P_B1F = 8388608;
  const long P_W2F = 8392704;
  const long P_B2F = 12587008;
  const long P_W1S = 12588032;
  const long P_B1S = 16782336;
  const long P_W2S = 16786432;
  const long P_B2S = 20980736;

  // ---- ws layout (floats) ----
  const long O_Q   = 0;
  const long O_K   = 4194304;
  const long O_V   = 8388608;
  const long O_CTX = 12582912;
  const long O_H   = 0;          // MLP hidden [4096,4096] (fwd; overlays QKV/CTX)
  const long O_AB  = 0;          // TTT abuf [R,4096]
  const long O_GB  = 524288;     // TTT Gbuf [R,1024]
  const long O_BAR = 12582912;   // TTT grid-barrier counters (dead CTX region)
  const long O_INF = 16787456;   // in_fast [4096,1024]
  const long O_INS = 20981760;   // in_slow [4096,1024]
  const long O_DF  = 25176064;   // 262,144
  const long O_DS  = 25438208;   // 65,536

  // --- seed fp32 masters directly into d_out (updated in place by TTT) ---
  {
    const long poff[8] = {P_W1F, P_B1F, P_W2F, P_B2F, P_W1S, P_B1S, P_W2S, P_B2S};
    const size_t psz[8] = {4194304, 4096, 4194304, 1024, 4194304, 4096, 4194304, 1024};
    for (int i = 0; i < 8; i++)
      hipMemcpyAsync(out + poff[i], d_in[6 + i], psz[i] * sizeof(float),
                     hipMemcpyDeviceToDevice, stream);
  }

  // --- per-chunk teach means ---
  compute_deltas<<<dim3(1281), 256, 0, stream>>>(teach, ws + O_DF, ws + O_DS);

  // --- Q/K/V projections ---
  {
    dim3 grd(16, 64);
    gemm_k<false, 0><<<grd, 256, 0, stream>>>(
        x, wq, ws + O_Q, nullptr, nullptr, 4096, 1024, 1024, 1024, 1024,
        4096, 0, 0, nullptr, 1, 0, 0, nullptr, 0.f);
    gemm_k<false, 0><<<grd, 256, 0, stream>>>(
        x, wk, ws + O_K, nullptr, nullptr, 4096, 1024, 1024, 1024, 1024,
        4096, 0, 0, nullptr, 1, 0, 0, nullptr, 0.f);
    gemm_k<false, 0><<<grd, 256, 0, stream>>>(
        x, wv, ws + O_V, nullptr, nullptr, 4096, 1024, 1024, 1024, 1024,
        4096, 0, 0, nullptr, 1, 0, 0, nullptr, 0.f);
  }

  // --- causal attention ---
  attn_kernel<<<dim3(32, 16, 2), 256, 0, stream>>>(ws + O_Q, ws + O_K, ws + O_V, ws + O_CTX);

  // --- in_fast = ctx @ wo ---
  gemm_k<false, 0><<<dim3(16, 64), 256, 0, stream>>>(
      ws + O_CTX, wo, ws + O_INF, nullptr, nullptr, 4096, 1024, 1024, 1024, 1024,
      4096, 0, 0, nullptr, 1, 0, 0, nullptr, 0.f);

  // --- MLP forwards with BASE params; full-width hidden buffer ---
  gemm_k<false, 1><<<dim3(64, 64), 256, 0, stream>>>(
      ws + O_INF, out + P_W1F, ws + O_H, nullptr, out + P_B1F,
      4096, 4096, 1024, 1024, 4096, 4096, 0, 0, nullptr, 1, 0, 0, nullptr, 0.f);
  gemm_k<false, 0><<<dim3(16, 64), 256, 0, stream>>>(
      ws + O_H, out + P_W2F, ws + O_INS, nullptr, out + P_B2F,
      4096, 1024, 4096, 4096, 1024, 4096, 0, 0, nullptr, 1, 0, 0, nullptr, 0.f);
  gemm_k<false, 1><<<dim3(64, 64), 256, 0, stream>>>(
      ws + O_INS, out + P_W1S, ws + O_H, nullptr, out + P_B1S,
      4096, 4096, 1024, 1024, 4096, 4096, 0, 0, nullptr, 1, 0, 0, nullptr, 0.f);
  gemm_k<false, 0><<<dim3(16, 64), 256, 0, stream>>>(
      ws + O_H, out + P_W2S, out, nullptr, out + P_B2S,
      4096, 1024, 4096, 4096, 1024, 4096, 0, 0, nullptr, 1, 0, 0, nullptr, 0.f);

  // --- TTT updates: ONE persistent kernel per level, weights on-chip ---
  hipMemsetAsync(ws + O_BAR, 0, 1024, stream);
  ttt_fused<16, 128><<<dim3(256), dim3(512), 0, stream>>>(
      ws + O_INF, ws + O_DF, out + P_W1F, out + P_B1F, out + P_W2F, out + P_B2F,
      ws + O_AB, ws + O_GB, (int*)(ws + O_BAR));
  hipMemsetAsync(ws + O_BAR, 0, 1024, stream);
  ttt_fused<64, 32><<<dim3(256), dim3(512), 0, stream>>>(
      ws + O_INS, ws + O_DS, out + P_W1S, out + P_B1S, out + P_W2S, out + P_B2S,
      ws + O_AB, ws + O_GB, (int*)(ws + O_BAR));
}